// Round 1
// baseline (1748.783 us; speedup 1.0000x reference)
//
#include <hip/hip_runtime.h>
#include <math.h>

namespace {
constexpr int NPTS = 1 << 21;      // 2097152 points
constexpr int NLVL = 16;           // levels
constexpr unsigned TMASK = 0x7FFFFu;   // T = 2^19, all hashed levels have size T
constexpr unsigned PI1 = 2654435761u;
constexpr unsigned PI2 = 805459861u;

struct Luts {
  float resf[NLVL];
  int off[NLVL];
};
}  // namespace

// thread = (point, level): i = n*16 + lvl. Output float2 store at out[i] is
// perfectly coalesced (out layout [n][lvl][2]).
__global__ __launch_bounds__(256) void henc_kernel(
    const float* __restrict__ coords, const float2* __restrict__ emb,
    float2* __restrict__ out, Luts p) {
  __shared__ float s_resf[NLVL];
  __shared__ int s_off[NLVL];
  // Static-index unroll (rule #20: dynamic index into by-value kernarg struct
  // would force a scratch copy). Thread 0 stages 128 B into LDS.
  if (threadIdx.x == 0) {
#pragma unroll
    for (int k = 0; k < NLVL; ++k) {
      s_resf[k] = p.resf[k];
      s_off[k] = p.off[k];
    }
  }
  __syncthreads();

  int i = blockIdx.x * 256 + threadIdx.x;
  int n = i >> 4;
  int lvl = i & 15;

  float cx = coords[3 * n + 0];
  float cy = coords[3 * n + 1];
  float cz = coords[3 * n + 2];

  float resf = s_resf[lvl];
  int off = s_off[lvl];
  int resi = (int)resf;
  bool hashed = lvl >= 7;  // (res+1)^3 > 2^19 from level 7 (res=80) upward
  unsigned s = (unsigned)(resi + 1);
  unsigned m1 = hashed ? PI1 : s;
  unsigned m2 = hashed ? PI2 : s * s;

  float sx = cx * resf, sy = cy * resf, sz = cz * resf;
  float bx = floorf(sx), by = floorf(sy), bz = floorf(sz);
  float fx = sx - bx, fy = sy - by, fz = sz - bz;
  int ix = (int)bx, iy = (int)by, iz = (int)bz;

  // clip(base + corner, 0, res) per reference (no-op for coords in [0,1), but
  // kept for exact semantics)
  int ix0 = min(max(ix, 0), resi), ix1 = min(max(ix + 1, 0), resi);
  int iy0 = min(max(iy, 0), resi), iy1 = min(max(iy + 1, 0), resi);
  int iz0 = min(max(iz, 0), resi), iz1 = min(max(iz + 1, 0), resi);

  // Per-dim index contributions: hash (x*1, y*PI1, z*PI2, XOR) or grid
  // (x, y*s, z*s^2, ADD). uint32 wraparound mul matches numpy.
  unsigned tx0 = (unsigned)ix0, tx1 = (unsigned)ix1;
  unsigned ty0 = (unsigned)iy0 * m1, ty1 = (unsigned)iy1 * m1;
  unsigned tz0 = (unsigned)iz0 * m2, tz1 = (unsigned)iz1 * m2;

  float wx0 = 1.0f - fx, wx1 = fx;
  float wy0 = 1.0f - fy, wy1 = fy;
  float wz0 = 1.0f - fz, wz1 = fz;

  float a0 = 0.0f, a1 = 0.0f;
#pragma unroll
  for (int c = 0; c < 8; ++c) {
    unsigned tx = (c & 1) ? tx1 : tx0;
    unsigned ty = (c & 2) ? ty1 : ty0;
    unsigned tz = (c & 4) ? tz1 : tz0;
    unsigned hidx = (tx ^ ty ^ tz) & TMASK;
    unsigned gidx = tx + ty + tz;
    int idx = (int)(hashed ? hidx : gidx);
    float2 e = emb[off + idx];
    float w = ((c & 1) ? wx1 : wx0) * ((c & 2) ? wy1 : wy0) *
              ((c & 4) ? wz1 : wz0);
    a0 = fmaf(w, e.x, a0);
    a1 = fmaf(w, e.y, a1);
  }
  out[i] = make_float2(a0, a1);
}

extern "C" void kernel_launch(void* const* d_in, const int* in_sizes, int n_in,
                              void* d_out, int out_size, void* d_ws,
                              size_t ws_size, hipStream_t stream) {
  const float* coords = (const float*)d_in[0];
  const float2* emb = (const float2*)d_in[1];
  float2* out = (float2*)d_out;

  // Replicate Python's level_params() bit-exactly with host libm doubles:
  // b = 32.0 ** (1/15); res_i = floor(16.0 * b**i). This nails the
  // floor-boundary levels (32, 64, 128, 256, 512) without guessing rounding.
  Luts p;
  double b = pow(32.0, 1.0 / 15.0);
  long long cum = 0;
  for (int i = 0; i < NLVL; ++i) {
    int r = (int)floor(16.0 * pow(b, (double)i));
    p.resf[i] = (float)r;
    p.off[i] = (int)cum;
    long long e3 = (long long)(r + 1) * (r + 1) * (r + 1);
    cum += e3 > 524288 ? 524288 : e3;
  }

  int total = NPTS * NLVL;  // 33,554,432 threads, one per (point, level)
  henc_kernel<<<dim3(total / 256), dim3(256), 0, stream>>>(coords, emb, out, p);
}

// Round 2
// 1559.080 us; speedup vs baseline: 1.1217x; 1.1217x over previous
//
#include <hip/hip_runtime.h>
#include <math.h>

namespace {
constexpr int NPTS = 1 << 21;      // 2097152 points
constexpr int NLVL = 16;           // levels
constexpr unsigned TMASK = 0x7FFFFu;   // T = 2^19; all hashed levels have size T
constexpr unsigned PI1 = 2654435761u;
constexpr unsigned PI2 = 805459861u;
constexpr int BLK = 256;
constexpr int BLOCKS_PER_LVL = NPTS / BLK;  // 8192

typedef float f2 __attribute__((ext_vector_type(2)));

struct Luts {
  float resf[NLVL];
  int off[NLVL];
};
}  // namespace

// Level-major grid: lvl = blockIdx >> 13. Blocks dispatch roughly in order, so
// the whole GPU processes one level at a time -> that level's table (<=4 MB)
// is L2-resident (replicated per XCD), independent of blockIdx->XCD mapping.
// Streaming traffic (coords, output) uses nt hints to avoid evicting table
// lines from L2. Output stores are 128B-strided; the memory-side Infinity
// Cache merges the 8 partial writes per 64B line before HBM.
__global__ __launch_bounds__(256) void henc_lvl_kernel(
    const float* __restrict__ coords, const f2* __restrict__ emb,
    f2* __restrict__ out, Luts p) {
  __shared__ float s_resf[NLVL];
  __shared__ int s_off[NLVL];
  // Static-index unroll (rule #20: dynamic index into by-value kernarg struct
  // would force a scratch copy).
  if (threadIdx.x == 0) {
#pragma unroll
    for (int k = 0; k < NLVL; ++k) {
      s_resf[k] = p.resf[k];
      s_off[k] = p.off[k];
    }
  }
  __syncthreads();

  int lvl = blockIdx.x >> 13;                       // block-uniform level
  int n = (blockIdx.x & (BLOCKS_PER_LVL - 1)) * BLK + (int)threadIdx.x;

  // Streaming coord reads: nt so they don't evict table lines from L2.
  float cx = __builtin_nontemporal_load(&coords[3 * n + 0]);
  float cy = __builtin_nontemporal_load(&coords[3 * n + 1]);
  float cz = __builtin_nontemporal_load(&coords[3 * n + 2]);

  float resf = s_resf[lvl];
  int off = s_off[lvl];
  int resi = (int)resf;
  bool hashed = lvl >= 7;  // (res+1)^3 > 2^19 from level 7 (res=80) upward
  unsigned s = (unsigned)(resi + 1);
  unsigned m1 = hashed ? PI1 : s;
  unsigned m2 = hashed ? PI2 : s * s;

  float sx = cx * resf, sy = cy * resf, sz = cz * resf;
  float bx = floorf(sx), by = floorf(sy), bz = floorf(sz);
  float fx = sx - bx, fy = sy - by, fz = sz - bz;
  int ix = (int)bx, iy = (int)by, iz = (int)bz;

  // clip(base + corner, 0, res) per reference semantics
  int ix0 = min(max(ix, 0), resi), ix1 = min(max(ix + 1, 0), resi);
  int iy0 = min(max(iy, 0), resi), iy1 = min(max(iy + 1, 0), resi);
  int iz0 = min(max(iz, 0), resi), iz1 = min(max(iz + 1, 0), resi);

  // Per-dim index terms: hash (x*1, y*PI1, z*PI2, XOR) or grid (x, y*s, z*s^2,
  // ADD). uint32 wraparound mul matches numpy.
  unsigned tx0 = (unsigned)ix0, tx1 = (unsigned)ix1;
  unsigned ty0 = (unsigned)iy0 * m1, ty1 = (unsigned)iy1 * m1;
  unsigned tz0 = (unsigned)iz0 * m2, tz1 = (unsigned)iz1 * m2;

  float wx0 = 1.0f - fx, wx1 = fx;
  float wy0 = 1.0f - fy, wy1 = fy;
  float wz0 = 1.0f - fz, wz1 = fz;

  float a0 = 0.0f, a1 = 0.0f;
#pragma unroll
  for (int c = 0; c < 8; ++c) {
    unsigned tx = (c & 1) ? tx1 : tx0;
    unsigned ty = (c & 2) ? ty1 : ty0;
    unsigned tz = (c & 4) ? tz1 : tz0;
    unsigned hidx = (tx ^ ty ^ tz) & TMASK;
    unsigned gidx = tx + ty + tz;
    int idx = (int)(hashed ? hidx : gidx);
    f2 e = emb[off + idx];  // plain load: WANT these cached in L2
    float w = ((c & 1) ? wx1 : wx0) * ((c & 2) ? wy1 : wy0) *
              ((c & 4) ? wz1 : wz0);
    a0 = fmaf(w, e.x, a0);
    a1 = fmaf(w, e.y, a1);
  }
  f2 r;
  r.x = a0;
  r.y = a1;
  // Strided (128B) nt store; partial lines merge in memory-side L3.
  __builtin_nontemporal_store(r, &out[n * NLVL + lvl]);
}

extern "C" void kernel_launch(void* const* d_in, const int* in_sizes, int n_in,
                              void* d_out, int out_size, void* d_ws,
                              size_t ws_size, hipStream_t stream) {
  const float* coords = (const float*)d_in[0];
  const f2* emb = (const f2*)d_in[1];
  f2* out = (f2*)d_out;

  // Replicate Python's level_params() bit-exactly with host libm doubles:
  // b = 32.0 ** (1/15); res_i = floor(16.0 * b**i).
  Luts p;
  double b = pow(32.0, 1.0 / 15.0);
  long long cum = 0;
  for (int i = 0; i < NLVL; ++i) {
    int r = (int)floor(16.0 * pow(b, (double)i));
    p.resf[i] = (float)r;
    p.off[i] = (int)cum;
    long long e3 = (long long)(r + 1) * (r + 1) * (r + 1);
    cum += e3 > 524288 ? 524288 : e3;
  }

  henc_lvl_kernel<<<dim3(NLVL * BLOCKS_PER_LVL), dim3(BLK), 0, stream>>>(
      coords, emb, out, p);
}